// Round 3
// baseline (624.544 us; speedup 1.0000x reference)
//
#include <hip/hip_runtime.h>

#define N_NODES 50000
#define N_EDGES 800000
#define HID 128
#define OUTD 10
#define HOPS 4
#define NGRAPH 128
#define CAP 64
#define OVF_MAX 4096

#define TILE_M 96
#define KC 32

// ---------- int64-vs-int32 layout probe ----------
__global__ void detect_kernel(const int* __restrict__ ei, int* __restrict__ flag) {
  if (threadIdx.x == 0 && blockIdx.x == 0) {
    int all0 = 1;
    for (int i = 0; i < 64; ++i) {
      if (ei[2 * i + 1] != 0) { all0 = 0; break; }
    }
    flag[0] = all0;
  }
}

__device__ __forceinline__ int ld_idx(const int* p, int i, int is64) {
  return is64 ? p[2 * i] : p[i];
}

// ---------- single-pass CSR-with-capacity fill; counter doubles as degree ----------
__global__ __launch_bounds__(256) void fill_kernel(const int* __restrict__ ei,
                                                   int* __restrict__ fillcnt,
                                                   int* __restrict__ col_fixed,
                                                   int* __restrict__ ovf_cnt,
                                                   int* __restrict__ ovf,
                                                   const int* __restrict__ flag) {
  int is64 = flag[0];
  int base = blockIdx.x * 1024;
#pragma unroll
  for (int u = 0; u < 4; ++u) {
    int e = base + u * 256 + threadIdx.x;
    if (e < N_EDGES) {
      int dst = ld_idx(ei, N_EDGES + e, is64);
      int src = ld_idx(ei, e, is64);
      int pos = atomicAdd(&fillcnt[dst], 1);
      if (pos < CAP) {
        col_fixed[dst * CAP + pos] = src;
      } else {
        int o = atomicAdd(ovf_cnt, 1);
        if (o < OVF_MAX) { ovf[2 * o] = dst; ovf[2 * o + 1] = src; }
      }
    }
  }
}

__global__ void dinv_kernel(const int* __restrict__ fillcnt, float* __restrict__ dinv) {
  int i = blockIdx.x * blockDim.x + threadIdx.x;
  if (i < N_NODES) dinv[i] = 1.0f / sqrtf(1.0f + (float)fillcnt[i]);
}

// ---------- fp32 GEMM: C[M][128] = A[M][128] @ W[128][128] (+bias) ----------
// 96x128 block tile, 192 threads (12x16), 8x8 per-thread register tile.
// A staged transposed (ds_read_b128 x2), W staged in 12-float-strided blocks
// (16 tc groups -> 8 banks x 2-way = conflict-free per m136).
__global__ __launch_bounds__(192) void gemm_kernel(const float* __restrict__ A,
                                                   const float* __restrict__ W,
                                                   const float* __restrict__ bias,
                                                   float* __restrict__ C, int M) {
  __shared__ float sAt[KC][TILE_M + 4];     // [32][100]
  __shared__ float sW2[KC][16][12];
  int tid = threadIdx.x;
  int row0 = blockIdx.x * TILE_M;
  int tc = tid & 15;
  int tr = tid >> 4;                         // 0..11

  float acc[8][8];
#pragma unroll
  for (int i = 0; i < 8; ++i)
#pragma unroll
    for (int j = 0; j < 8; ++j) acc[i][j] = 0.f;

  for (int kc = 0; kc < HID; kc += KC) {
    // stage A chunk transposed: 96 rows x 32 k = 768 float4, 4 per thread
#pragma unroll
    for (int it = 0; it < 4; ++it) {
      int f = it * 192 + tid;              // 0..767
      int r = f >> 3;                      // 0..95
      int k4 = (f & 7) << 2;               // 0..28
      int gr = row0 + r;
      float4 v = make_float4(0.f, 0.f, 0.f, 0.f);
      if (gr < M) v = *(const float4*)(A + (size_t)gr * HID + kc + k4);
      sAt[k4 + 0][r] = v.x;
      sAt[k4 + 1][r] = v.y;
      sAt[k4 + 2][r] = v.z;
      sAt[k4 + 3][r] = v.w;
    }
    // stage W chunk: 32 k x 128 cols = 1024 float4, 6 iters guarded
#pragma unroll
    for (int it = 0; it < 6; ++it) {
      int f = it * 192 + tid;
      if (f < 1024) {
        int k = f >> 5;                    // 0..31
        int c4 = (f & 31) << 2;            // 0..124
        float4 v = *(const float4*)(W + (size_t)(kc + k) * HID + c4);
        *(float4*)&sW2[k][c4 >> 3][c4 & 7] = v;
      }
    }
    __syncthreads();

#pragma unroll 2
    for (int k = 0; k < KC; ++k) {
      float4 a0 = *(const float4*)&sAt[k][tr * 8];
      float4 a1 = *(const float4*)&sAt[k][tr * 8 + 4];
      float4 w0 = *(const float4*)&sW2[k][tc][0];
      float4 w1 = *(const float4*)&sW2[k][tc][4];
      float av[8] = {a0.x, a0.y, a0.z, a0.w, a1.x, a1.y, a1.z, a1.w};
      float wv[8] = {w0.x, w0.y, w0.z, w0.w, w1.x, w1.y, w1.z, w1.w};
#pragma unroll
      for (int i = 0; i < 8; ++i)
#pragma unroll
        for (int j = 0; j < 8; ++j) acc[i][j] += av[i] * wv[j];
    }
    __syncthreads();
  }

  float4 bv0 = make_float4(0.f, 0.f, 0.f, 0.f);
  float4 bv1 = bv0;
  if (bias) {
    bv0 = *(const float4*)(bias + tc * 8);
    bv1 = *(const float4*)(bias + tc * 8 + 4);
  }
#pragma unroll
  for (int i = 0; i < 8; ++i) {
    int gr = row0 + tr * 8 + i;
    if (gr < M) {
      float4 o0, o1;
      o0.x = acc[i][0] + bv0.x; o0.y = acc[i][1] + bv0.y;
      o0.z = acc[i][2] + bv0.z; o0.w = acc[i][3] + bv0.w;
      o1.x = acc[i][4] + bv1.x; o1.y = acc[i][5] + bv1.y;
      o1.z = acc[i][6] + bv1.z; o1.w = acc[i][7] + bv1.w;
      *(float4*)(C + (size_t)gr * HID + tc * 8) = o0;
      *(float4*)(C + (size_t)gr * HID + tc * 8 + 4) = o1;
    }
  }
}

// ---------- GCN aggregate (gather): out = agg + xw*selfnorm + b ----------
__global__ __launch_bounds__(256) void agg_kernel(const float* __restrict__ xw,
                                                  const int* __restrict__ fillcnt,
                                                  const int* __restrict__ col_fixed,
                                                  const float* __restrict__ dinv,
                                                  const float* __restrict__ bias,
                                                  const int* __restrict__ ovf_cnt,
                                                  const int* __restrict__ ovf,
                                                  float* __restrict__ out, int relu) {
  int wave = threadIdx.x >> 6;
  int lane = threadIdx.x & 63;
  int node = blockIdx.x * 4 + wave;
  if (node >= N_NODES) return;

  const float2* xr = (const float2*)xw;
  float di = dinv[node];
  float sn = di * di;
  float2 v = xr[(size_t)node * 64 + lane];
  float2 b = ((const float2*)bias)[lane];
  float2 acc;
  acc.x = v.x * sn + b.x;
  acc.y = v.y * sn + b.y;

  int deg = fillcnt[node];
  int m = min(deg, CAP);
  int cidx = 0;
  float cw = 0.f;
  if (lane < m) {
    cidx = col_fixed[node * CAP + lane];
    cw = dinv[cidx];
  }
  for (int j = 0; j < m; ++j) {
    int src = __builtin_amdgcn_readlane(cidx, j);
    float w = __uint_as_float((unsigned)__builtin_amdgcn_readlane((int)__float_as_uint(cw), j)) * di;
    float2 u = xr[(size_t)src * 64 + lane];
    acc.x += u.x * w;
    acc.y += u.y * w;
  }
  if (deg > CAP) {
    int novf = min(*ovf_cnt, OVF_MAX);
    for (int o = 0; o < novf; ++o) {
      if (ovf[2 * o] == node) {
        int src = ovf[2 * o + 1];
        float w = dinv[src] * di;
        float2 u = xr[(size_t)src * 64 + lane];
        acc.x += u.x * w;
        acc.y += u.y * w;
      }
    }
  }
  if (relu) {
    acc.x = fmaxf(acc.x, 0.f);
    acc.y = fmaxf(acc.y, 0.f);
  }
  ((float2*)out)[(size_t)node * 64 + lane] = acc;
}

// ---------- classifier GEMM (128->10) + per-graph pooling + counts ----------
__global__ __launch_bounds__(256) void pool_kernel(const float* __restrict__ h,
                                                   const float* __restrict__ Wc,
                                                   const float* __restrict__ bc,
                                                   const int* __restrict__ batch,
                                                   float* __restrict__ pool,
                                                   float* __restrict__ cnt, int M,
                                                   const int* __restrict__ flag) {
  __shared__ float sW[HID * OUTD];
  __shared__ float spool[NGRAPH * OUTD];
  __shared__ float scount[NGRAPH];
  int tid = threadIdx.x;
  for (int i = tid; i < HID * OUTD; i += 256) sW[i] = Wc[i];
  for (int i = tid; i < NGRAPH * OUTD; i += 256) spool[i] = 0.f;
  if (tid < NGRAPH) scount[tid] = 0.f;
  __syncthreads();

  int row = blockIdx.x * 256 + tid;
  if (row < M) {
    int is64 = flag[0];
    float y[OUTD];
#pragma unroll
    for (int o = 0; o < OUTD; ++o) y[o] = bc[o];
    const float4* hr = (const float4*)(h + (size_t)row * HID);
    for (int k4 = 0; k4 < 32; ++k4) {
      float4 hv = hr[k4];
      int kb = k4 * 4;
#pragma unroll
      for (int o = 0; o < OUTD; ++o) {
        y[o] += hv.x * sW[(kb + 0) * OUTD + o];
        y[o] += hv.y * sW[(kb + 1) * OUTD + o];
        y[o] += hv.z * sW[(kb + 2) * OUTD + o];
        y[o] += hv.w * sW[(kb + 3) * OUTD + o];
      }
    }
    int g = ld_idx(batch, row, is64);
#pragma unroll
    for (int o = 0; o < OUTD; ++o) atomicAdd(&spool[g * OUTD + o], y[o]);
    atomicAdd(&scount[g], 1.0f);
  }
  __syncthreads();
  for (int i = tid; i < NGRAPH * OUTD; i += 256) {
    float v = spool[i];
    if (v != 0.f) atomicAdd(&pool[i], v);
  }
  if (tid < NGRAPH && scount[tid] != 0.f) atomicAdd(&cnt[tid], scount[tid]);
}

__global__ void finalize_kernel(const float* __restrict__ pool,
                                const float* __restrict__ cnt,
                                float* __restrict__ out) {
  int i = blockIdx.x * blockDim.x + threadIdx.x;
  if (i < NGRAPH * OUTD) {
    float c = cnt[i / OUTD];
    out[i] = pool[i] / fmaxf(c, 1.0f);
  }
}

extern "C" void kernel_launch(void* const* d_in, const int* in_sizes, int n_in,
                              void* d_out, int out_size, void* d_ws, size_t ws_size,
                              hipStream_t stream) {
  const float* x      = (const float*)d_in[0];
  const int*   ei     = (const int*)d_in[1];
  const int*   batch  = (const int*)d_in[2];
  const float* W_in   = (const float*)d_in[3];
  const float* b_in   = (const float*)d_in[4];
  const float* W_hops = (const float*)d_in[5];
  const float* b_hops = (const float*)d_in[6];
  const float* W_cls  = (const float*)d_in[7];
  const float* b_cls  = (const float*)d_in[8];
  float* out = (float*)d_out;

  char* ws = (char*)d_ws;
  size_t off = 0;
  auto alloc = [&](size_t bytes) -> void* {
    void* p = ws + off;
    off += (bytes + 255) & ~(size_t)255;
    return p;
  };

  // zero-initialized region first
  int*   fillcnt = (int*)alloc(N_NODES * 4);
  int*   ovf_cnt = (int*)alloc(4);
  float* pool    = (float*)alloc(NGRAPH * OUTD * 4);
  float* cnt     = (float*)alloc(NGRAPH * 4);
  size_t zero_bytes = off;
  int*   flag    = (int*)alloc(4);
  float* dinv    = (float*)alloc(N_NODES * 4);
  int*   ovf     = (int*)alloc(OVF_MAX * 2 * 4);
  int*   col_fixed = (int*)alloc((size_t)N_NODES * CAP * 4);
  float* bufA    = (float*)alloc((size_t)N_NODES * HID * 4);  // h
  float* bufB    = (float*)alloc((size_t)N_NODES * HID * 4);  // xw
  (void)ws_size; (void)in_sizes; (void)n_in; (void)out_size;

  hipMemsetAsync(d_ws, 0, zero_bytes, stream);
  detect_kernel<<<1, 64, 0, stream>>>(ei, flag);
  fill_kernel<<<(N_EDGES + 1023) / 1024, 256, 0, stream>>>(ei, fillcnt, col_fixed, ovf_cnt, ovf, flag);
  dinv_kernel<<<(N_NODES + 255) / 256, 256, 0, stream>>>(fillcnt, dinv);

  int gblocks = (N_NODES + TILE_M - 1) / TILE_M;
  // encoder: h = x @ W_in + b_in  -> bufA
  gemm_kernel<<<gblocks, 192, 0, stream>>>(x, W_in, b_in, bufA, N_NODES);

  for (int i = 0; i < HOPS; ++i) {
    gemm_kernel<<<gblocks, 192, 0, stream>>>(bufA, W_hops + (size_t)i * HID * HID, nullptr, bufB, N_NODES);
    agg_kernel<<<(N_NODES + 3) / 4, 256, 0, stream>>>(bufB, fillcnt, col_fixed, dinv,
                                                      b_hops + (size_t)i * HID, ovf_cnt, ovf,
                                                      bufA, (i < HOPS - 1) ? 1 : 0);
  }

  pool_kernel<<<(N_NODES + 255) / 256, 256, 0, stream>>>(bufA, W_cls, b_cls, batch, pool, cnt, N_NODES, flag);
  finalize_kernel<<<(NGRAPH * OUTD + 255) / 256, 256, 0, stream>>>(pool, cnt, out);
}